// Round 7
// baseline (217.629 us; speedup 1.0000x reference)
//
#include <hip/hip_runtime.h>

// WaveletFeatureAugmentation as passthrough-copy + skinny MFMA GEMM:
//   aug[16384][14] = X[16384][4096] @ CM^T[4096][14]  (CM = W @ 9-level db4
//   cascade, verified rounds 3-6), done in bf16 MFMA 16x16x32, f32 accumulate.
// Kernel 1 builds CM^T padded to 16 rows in bf16 (d_ws, 128 KB).
// Kernel 2: block = 256 thr (4 waves) x 16 rows; wave owns a k-quarter (1024).
// Main loop has NO LDS, NO barriers, NO shuffles: per 32-k step each lane
// loads 2xfloat4 of x (A-frag rows = lane&15, k = 8*(lane>>4)+j), streams the
// same data to out (f32 passthrough), converts to bf16, one b128 CM load
// (L2-hot), one MFMA. Epilogue: 4 KB LDS partial combine + bias.

#define ROWS 16384          // 32*512
#define N0   4096
#define OUTW 4110           // 4096 + 14

typedef __attribute__((ext_vector_type(8))) short bf16x8;
typedef __attribute__((ext_vector_type(4))) float f32x4;

__device__ __constant__ float c_dlo[8] = {
    -0.010597401784997278f,  0.032883011666982945f,
     0.030841381835986965f, -0.18703481171888114f,
    -0.02798376941698385f,   0.6308807679295904f,
     0.7148465705525415f,    0.23037781330885523f};

__device__ __forceinline__ short f2bf(float f) {   // RNE float->bf16 (no NaN in data)
    unsigned u = __float_as_uint(f);
    unsigned r = u + 0x7FFFu + ((u >> 16) & 1u);
    return (short)(r >> 16);
}

// ---- CM builder (adjoint cascade, verified rounds 3-6); now emits bf16 CM^T
//      padded to 16 rows (rows 14,15 zero via zero W row). ----
__device__ __forceinline__ float adj_contrib(const float* __restrict__ g,
                                             int t, int nout) {
    int i0 = t >> 1;        if (i0 < 0) i0 = 0;
    int i1 = (t + 6) >> 1;  if (i1 > nout - 1) i1 = nout - 1;
    float acc = 0.f;
    for (int i = i0; i <= i1; ++i)
        acc = fmaf(g[i], c_dlo[2 * i + 1 - t], acc);
    return acc;
}

__global__ __launch_bounds__(256) void build_cm_kernel(
    const float* __restrict__ W, unsigned short* __restrict__ cmT)
{
    __shared__ float A[4096];
    __shared__ float B[2051];
    const int o = blockIdx.x, tid = threadIdx.x;   // o in [0,16)
    if (tid < 14) B[tid] = (o < 14) ? W[o * 14 + tid] : 0.f;
    __syncthreads();
    const int ns[10] = {14, 22, 38, 70, 134, 262, 518, 1029, 2051, 4096};
    float* g = B;
    float* h = A;
    for (int lev = 1; lev <= 9; ++lev) {
        const int n = ns[lev], nout = ns[lev - 1];
        const int s2 = 2 * (n - nout);
        for (int s = tid; s < n; s += 256) {
            float v = adj_contrib(g, s, nout);
            if (s <= 5)  v += adj_contrib(g, -1 - s, nout);
            if (s >= s2) v += adj_contrib(g, 2 * n - 1 - s, nout);
            h[s] = v;
        }
        __syncthreads();
        float* t2 = g; g = h; h = t2;
    }
    for (int c = tid; c < 4096; c += 256)
        cmT[o * 4096 + c] = (unsigned short)f2bf(g[c]);
}

// ---- main fused kernel ----
__global__ __launch_bounds__(256) void wavelet_aug_mfma(
    const float* __restrict__ x, const unsigned short* __restrict__ cmT,
    const float* __restrict__ b, float* __restrict__ out)
{
    __shared__ float parts[4][64][4];              // 4 KB
    const int tid  = threadIdx.x;
    const int wave = tid >> 6;
    const int lane = tid & 63;
    const int r    = lane & 15;                    // A row / B col (n)
    const int g    = lane >> 4;                    // k-group within 32-k step
    const int row0 = blockIdx.x << 4;
    const int kq   = wave << 10;                   // this wave's k-quarter

    const float*          xr = x   + (size_t)(row0 + r) * N0;
    float*              orow = out + (size_t)(row0 + r) * OUTW;
    const unsigned short* cr = cmT + r * N0;

    f32x4 acc = {0.f, 0.f, 0.f, 0.f};

    // 32 MFMA steps of K=32; lane covers k = kq + s*32 + g*8 + [0,8)
    #pragma unroll 8
    for (int s = 0; s < 32; ++s) {
        const int k = kq + (s << 5) + (g << 3);
        const float4 a0 = *reinterpret_cast<const float4*>(xr + k);
        const float4 a1 = *reinterpret_cast<const float4*>(xr + k + 4);
        const bf16x8 bv = *reinterpret_cast<const bf16x8*>(cr + k);

        // passthrough (out rows only 8B-aligned -> float2 stores)
        *reinterpret_cast<float2*>(orow + k)     = make_float2(a0.x, a0.y);
        *reinterpret_cast<float2*>(orow + k + 2) = make_float2(a0.z, a0.w);
        *reinterpret_cast<float2*>(orow + k + 4) = make_float2(a1.x, a1.y);
        *reinterpret_cast<float2*>(orow + k + 6) = make_float2(a1.z, a1.w);

        bf16x8 av;
        av[0] = f2bf(a0.x); av[1] = f2bf(a0.y);
        av[2] = f2bf(a0.z); av[3] = f2bf(a0.w);
        av[4] = f2bf(a1.x); av[5] = f2bf(a1.y);
        av[6] = f2bf(a1.z); av[7] = f2bf(a1.w);

        acc = __builtin_amdgcn_mfma_f32_16x16x32_bf16(av, bv, acc, 0, 0, 0);
    }

    // combine the 4 k-quarter partials
    parts[wave][lane][0] = acc[0];
    parts[wave][lane][1] = acc[1];
    parts[wave][lane][2] = acc[2];
    parts[wave][lane][3] = acc[3];
    __syncthreads();

    if (tid < 64) {
        const float4 p0 = *reinterpret_cast<const float4*>(parts[0][tid]);
        const float4 p1 = *reinterpret_cast<const float4*>(parts[1][tid]);
        const float4 p2 = *reinterpret_cast<const float4*>(parts[2][tid]);
        const float4 p3 = *reinterpret_cast<const float4*>(parts[3][tid]);
        const int col   = tid & 15;                // C/D: col = lane&15
        const int rbase = (tid >> 4) << 2;         // row = (lane>>4)*4 + reg
        if (col < 14) {
            const float bb = b[col];
            float s0 = p0.x + p1.x + p2.x + p3.x + bb;
            float s1 = p0.y + p1.y + p2.y + p3.y + bb;
            float s2 = p0.z + p1.z + p2.z + p3.z + bb;
            float s3 = p0.w + p1.w + p2.w + p3.w + bb;
            out[(size_t)(row0 + rbase + 0) * OUTW + N0 + col] = s0;
            out[(size_t)(row0 + rbase + 1) * OUTW + N0 + col] = s1;
            out[(size_t)(row0 + rbase + 2) * OUTW + N0 + col] = s2;
            out[(size_t)(row0 + rbase + 3) * OUTW + N0 + col] = s3;
        }
    }
}

extern "C" void kernel_launch(void* const* d_in, const int* in_sizes, int n_in,
                              void* d_out, int out_size, void* d_ws, size_t ws_size,
                              hipStream_t stream) {
    const float* x = (const float*)d_in[0];   // [32,512,4096]
    const float* W = (const float*)d_in[1];   // [14,14]
    const float* b = (const float*)d_in[2];   // [14]
    float* out = (float*)d_out;               // [32,512,4110]
    unsigned short* cmT = (unsigned short*)d_ws;  // [16][4096] bf16 CM^T

    build_cm_kernel<<<16, 256, 0, stream>>>(W, cmT);
    wavelet_aug_mfma<<<ROWS / 16, 256, 0, stream>>>(x, cmT, b, out);
}

// Round 8
// 154.077 us; speedup vs baseline: 1.4125x; 1.4125x over previous
//
#include <hip/hip_runtime.h>

// WaveletFeatureAugmentation as passthrough + skinny MFMA GEMM with LDS-staged
// A-operand:
//   aug[16384][14] = X[16384][4096] @ CM^T[4096][14], bf16 MFMA 16x16x32.
// CM = W @ 9-level db4 cascade (adjoint builder verified rounds 3-7).
// Main kernel: block = 256 thr (4 waves) x 16 rows, K-loop BK=256:
//   - coalesced float4 x loads (4/thread, batched -> in flight together)
//   - passthrough stores from the same registers (contiguous)
//   - bf16 cvt + ds_write_b64 into [chunk][row] tile, 272B chunk stride
//     (16B-aligned, conflict-free for both b64 writes and b128 A-frag reads)
//   - B-frags (CM, L2/L3-hot 128 KB) loaded global->VGPR, 2 b128/lane/iter
//   - 2 x (ds_read_b128 + MFMA) per wave per iter; wave owns a 64-wide k-slice
// Epilogue: 4-way k-partial combine in LDS + bias (layout verified round 7).

#define ROWS 16384          // 32*512
#define N0   4096
#define OUTW 4110           // 4096 + 14

typedef __attribute__((ext_vector_type(8))) short bf16x8;
typedef __attribute__((ext_vector_type(4))) float f32x4;

__device__ __constant__ float c_dlo[8] = {
    -0.010597401784997278f,  0.032883011666982945f,
     0.030841381835986965f, -0.18703481171888114f,
    -0.02798376941698385f,   0.6308807679295904f,
     0.7148465705525415f,    0.23037781330885523f};

__device__ __forceinline__ unsigned short f2bf(float f) {  // RNE float->bf16
    unsigned u = __float_as_uint(f);
    return (unsigned short)((u + 0x7FFFu + ((u >> 16) & 1u)) >> 16);
}

// ---- CM builder (adjoint cascade, verified rounds 3-7); bf16 CM^T padded
//      to 16 rows (rows 14,15 zero). ----
__device__ __forceinline__ float adj_contrib(const float* __restrict__ g,
                                             int t, int nout) {
    int i0 = t >> 1;        if (i0 < 0) i0 = 0;
    int i1 = (t + 6) >> 1;  if (i1 > nout - 1) i1 = nout - 1;
    float acc = 0.f;
    for (int i = i0; i <= i1; ++i)
        acc = fmaf(g[i], c_dlo[2 * i + 1 - t], acc);
    return acc;
}

__global__ __launch_bounds__(256) void build_cm_kernel(
    const float* __restrict__ W, unsigned short* __restrict__ cmT)
{
    __shared__ float A[4096];
    __shared__ float B[2051];
    const int o = blockIdx.x, tid = threadIdx.x;   // o in [0,16)
    if (tid < 14) B[tid] = (o < 14) ? W[o * 14 + tid] : 0.f;
    __syncthreads();
    const int ns[10] = {14, 22, 38, 70, 134, 262, 518, 1029, 2051, 4096};
    float* g = B;
    float* h = A;
    for (int lev = 1; lev <= 9; ++lev) {
        const int n = ns[lev], nout = ns[lev - 1];
        const int s2 = 2 * (n - nout);
        for (int s = tid; s < n; s += 256) {
            float v = adj_contrib(g, s, nout);
            if (s <= 5)  v += adj_contrib(g, -1 - s, nout);
            if (s >= s2) v += adj_contrib(g, 2 * n - 1 - s, nout);
            h[s] = v;
        }
        __syncthreads();
        float* t2 = g; g = h; h = t2;
    }
    for (int c = tid; c < 4096; c += 256)
        cmT[o * 4096 + c] = f2bf(g[c]);
}

// ---- main fused kernel ----
__global__ __launch_bounds__(256) void wavelet_aug_mfma(
    const float* __restrict__ x, const unsigned short* __restrict__ cmT,
    const float* __restrict__ b, float* __restrict__ out)
{
    // X tile: 32 k-chunks (8 bf16 each) x 16 rows, chunk stride 272 B (16x17:
    // 16B-aligned; 68 dwords = 4 mod 32 banks -> conflict-free phases).
    __shared__ __align__(16) unsigned short xt[32][136];
    __shared__ float parts[4][64][4];

    const int tid  = threadIdx.x;
    const int wave = tid >> 6;
    const int lane = tid & 63;
    const int r    = lane & 15;          // A row / B col
    const int g    = lane >> 4;          // k-subgroup
    const int row0 = blockIdx.x << 4;

    const unsigned short* cr = cmT + r * N0;
    f32x4 acc = {0.f, 0.f, 0.f, 0.f};

    #pragma unroll 2
    for (int it = 0; it < 16; ++it) {
        const int kb = it << 8;

        // B-fragment prefetch (identical for all blocks; L2/L3-hot)
        const int kbw = kb + (wave << 6) + (g << 3);
        const bf16x8 bv0 = *reinterpret_cast<const bf16x8*>(cr + kbw);
        const bf16x8 bv1 = *reinterpret_cast<const bf16x8*>(cr + kbw + 32);

        // stage: wave stages rows {wave, wave+4, wave+8, wave+12}; lane owns
        // float4 at column 4*lane -> 1 KB contiguous per instruction.
        float4 a[4];
        #pragma unroll
        for (int i = 0; i < 4; ++i) {
            const int rr = (i << 2) + wave;
            a[i] = *reinterpret_cast<const float4*>(
                x + (size_t)(row0 + rr) * N0 + kb + (lane << 2));
        }
        #pragma unroll
        for (int i = 0; i < 4; ++i) {
            const int rr = (i << 2) + wave;
            float* orow = out + (size_t)(row0 + rr) * OUTW + kb + (lane << 2);
            reinterpret_cast<float2*>(orow)[0] = make_float2(a[i].x, a[i].y);
            reinterpret_cast<float2*>(orow)[1] = make_float2(a[i].z, a[i].w);
            ushort4 u;
            u.x = f2bf(a[i].x); u.y = f2bf(a[i].y);
            u.z = f2bf(a[i].z); u.w = f2bf(a[i].w);
            *reinterpret_cast<ushort4*>(
                &xt[lane >> 1][(rr << 3) + ((lane & 1) << 2)]) = u;
        }
        __syncthreads();

        // MFMA: wave owns k-slice [wave*64, wave*64+64) of this BK tile
        #pragma unroll
        for (int t = 0; t < 2; ++t) {
            const int ch = (wave << 3) + (t << 2) + g;
            const bf16x8 av =
                *reinterpret_cast<const bf16x8*>(&xt[ch][r << 3]);
            acc = __builtin_amdgcn_mfma_f32_16x16x32_bf16(
                av, t ? bv1 : bv0, acc, 0, 0, 0);
        }
        __syncthreads();
    }

    // combine the 4 k-quarter partials (C/D map: col=lane&15, row=4*(lane>>4)+j)
    parts[wave][lane][0] = acc[0];
    parts[wave][lane][1] = acc[1];
    parts[wave][lane][2] = acc[2];
    parts[wave][lane][3] = acc[3];
    __syncthreads();

    if (tid < 64) {
        const float4 p0 = *reinterpret_cast<const float4*>(parts[0][tid]);
        const float4 p1 = *reinterpret_cast<const float4*>(parts[1][tid]);
        const float4 p2 = *reinterpret_cast<const float4*>(parts[2][tid]);
        const float4 p3 = *reinterpret_cast<const float4*>(parts[3][tid]);
        const int col   = tid & 15;
        const int rbase = (tid >> 4) << 2;
        if (col < 14) {
            const float bb = b[col];
            out[(size_t)(row0 + rbase + 0) * OUTW + N0 + col] = p0.x + p1.x + p2.x + p3.x + bb;
            out[(size_t)(row0 + rbase + 1) * OUTW + N0 + col] = p0.y + p1.y + p2.y + p3.y + bb;
            out[(size_t)(row0 + rbase + 2) * OUTW + N0 + col] = p0.z + p1.z + p2.z + p3.z + bb;
            out[(size_t)(row0 + rbase + 3) * OUTW + N0 + col] = p0.w + p1.w + p2.w + p3.w + bb;
        }
    }
}

extern "C" void kernel_launch(void* const* d_in, const int* in_sizes, int n_in,
                              void* d_out, int out_size, void* d_ws, size_t ws_size,
                              hipStream_t stream) {
    const float* x = (const float*)d_in[0];   // [32,512,4096]
    const float* W = (const float*)d_in[1];   // [14,14]
    const float* b = (const float*)d_in[2];   // [14]
    float* out = (float*)d_out;               // [32,512,4110]
    unsigned short* cmT = (unsigned short*)d_ws;  // [16][4096] bf16 CM^T

    build_cm_kernel<<<16, 256, 0, stream>>>(W, cmT);
    wavelet_aug_mfma<<<ROWS / 16, 256, 0, stream>>>(x, cmT, b, out);
}